// Round 13
// baseline (310.623 us; speedup 1.0000x reference)
//
#include <hip/hip_runtime.h>
#include <math.h>

#define TPB 256
#define TPB_H 512
#define TPB_BIN 1024
#define CSR_TPB 1024
#define NB_MAX 512      // coarse buckets of 256 nodes -> supports N <= 131072
#define BKT_SHIFT 8
#define BKT_NODES 256
#define BIN_CHUNK 8192

__device__ inline float bfLO(unsigned u) { return __uint_as_float(u << 16); }
__device__ inline float bfHI(unsigned u) { return __uint_as_float(u & 0xffff0000u); }
__device__ inline unsigned short f2bf(float f) {
    unsigned int x = __float_as_uint(f);
    return (unsigned short)((x + 0x7fffu + ((x >> 16) & 1u)) >> 16);  // RNE
}

// ---------------- pass A: coarse bucket histogram (LDS, int4 loads) ----------------
__global__ void k_hist_coarse(const int* __restrict__ dst, int* __restrict__ bucketCnt,
                              int e, int nb) {
    __shared__ int h[NB_MAX];
    for (int i = threadIdx.x; i < nb; i += TPB_H) h[i] = 0;
    __syncthreads();
    int e4 = e >> 2;
    const int4* d4 = (const int4*)dst;
    for (long long i = (long long)blockIdx.x * TPB_H + threadIdx.x; i < e4;
         i += (long long)gridDim.x * TPB_H) {
        int4 v = d4[i];
        atomicAdd(&h[v.x >> BKT_SHIFT], 1);
        atomicAdd(&h[v.y >> BKT_SHIFT], 1);
        atomicAdd(&h[v.z >> BKT_SHIFT], 1);
        atomicAdd(&h[v.w >> BKT_SHIFT], 1);
    }
    if (blockIdx.x == 0)
        for (int i = (e4 << 2) + threadIdx.x; i < e; i += TPB_H)
            atomicAdd(&h[dst[i] >> BKT_SHIFT], 1);
    __syncthreads();
    for (int i = threadIdx.x; i < nb; i += TPB_H)
        if (h[i]) atomicAdd(&bucketCnt[i], h[i]);
}

// ---------------- parallel bucket scan (1 block) ----------------
__global__ void k_scanb(const int* __restrict__ cnt, int* __restrict__ boff,
                        int* __restrict__ bcur, int* __restrict__ off_nodes,
                        int nb, int e, int n) {
    __shared__ int lds[NB_MAX];
    int t = threadIdx.x;
    int v = (t < nb) ? cnt[t] : 0;
    lds[t] = v;
    __syncthreads();
    for (int d = 1; d < NB_MAX; d <<= 1) {
        int x = (t >= d) ? lds[t - d] : 0;
        __syncthreads();
        lds[t] += x;
        __syncthreads();
    }
    int excl = lds[t] - v;
    if (t < nb) { boff[t] = excl; bcur[t] = excl; }
    if (t == nb - 1) boff[nb] = lds[t];
    if (t == 0) off_nodes[n] = e;
}

// ---------------- pass B: bin packed (src | local_dst<<24) by coarse bucket ----------------
__global__ void k_bin_pairs(const int* __restrict__ src, const int* __restrict__ dst,
                            int* __restrict__ bucketCur, unsigned* __restrict__ pairs,
                            int e, int nb) {
    __shared__ int h[NB_MAX];
    __shared__ int base[NB_MAX];
    int e0 = blockIdx.x * BIN_CHUNK;
    int e1 = min(e0 + BIN_CHUNK, e);
    for (int i = threadIdx.x; i < nb; i += TPB_BIN) h[i] = 0;
    __syncthreads();
    for (int i = e0 + threadIdx.x; i < e1; i += TPB_BIN)
        atomicAdd(&h[dst[i] >> BKT_SHIFT], 1);
    __syncthreads();
    for (int i = threadIdx.x; i < nb; i += TPB_BIN) {
        int c = h[i];
        base[i] = c ? atomicAdd(&bucketCur[i], c) : 0;
        h[i] = 0;  // reuse as intra-block cursor
    }
    __syncthreads();
    for (int i = e0 + threadIdx.x; i < e1; i += TPB_BIN) {
        int d = dst[i];
        int b = d >> BKT_SHIFT;
        int pos = base[b] + atomicAdd(&h[b], 1);
        pairs[pos] = ((unsigned)(d & (BKT_NODES - 1)) << 24) | (unsigned)src[i];
    }
}

// ---------------- pass C: per-bucket fine CSR + node offsets + dinv ----------------
__global__ void k_bucket_csr(const unsigned* __restrict__ pairs, const int* __restrict__ bucketOff,
                             int* __restrict__ off_nodes, float* __restrict__ dinv,
                             int* __restrict__ csr, int n) {
    __shared__ int hist[BKT_NODES];
    __shared__ int offl[BKT_NODES];
    __shared__ int cur[BKT_NODES];
    int b = blockIdx.x;
    int t = threadIdx.x;  // CSR_TPB threads
    int e0 = bucketOff[b], e1 = bucketOff[b + 1];
    int nbase = b << BKT_SHIFT;
    if (t < BKT_NODES) hist[t] = 0;
    __syncthreads();
    for (int e = e0 + t; e < e1; e += CSR_TPB)
        atomicAdd(&hist[pairs[e] >> 24], 1);
    __syncthreads();
    int v = 0;
    if (t < BKT_NODES) { v = hist[t]; offl[t] = v; }
    __syncthreads();
    for (int d = 1; d < BKT_NODES; d <<= 1) {
        int x = 0;
        if (t < BKT_NODES && t >= d) x = offl[t - d];
        __syncthreads();
        if (t < BKT_NODES) offl[t] += x;
        __syncthreads();
    }
    if (t < BKT_NODES) {
        int excl = offl[t] - v;
        cur[t] = excl;
        int nd = nbase + t;
        if (nd < n) {
            off_nodes[nd] = e0 + excl;
            dinv[nd] = rsqrtf((float)(v + 1));  // +1 self loop
        }
    }
    __syncthreads();
    for (int e = e0 + t; e < e1; e += CSR_TPB) {
        unsigned p = pairs[e];
        int l = (int)(p >> 24);
        int pos = e0 + atomicAdd(&cur[l], 1);
        csr[pos] = (int)(p & 0xffffffu);
    }
}

// ---------------- xp4 = float4(dinv*x, pad) ----------------
__global__ void k_scale4(const float* __restrict__ x, const float* __restrict__ dinv,
                         float4* __restrict__ xp, int n) {
    int i = blockIdx.x * TPB + threadIdx.x;
    if (i >= n) return;
    float di = dinv[i];
    xp[i] = make_float4(x[i * 3] * di, x[i * 3 + 1] * di, x[i * 3 + 2] * di, 0.0f);
}

// ---------------- fused gather(F=3, float4 rows) + mm1 + relu -> T1' = dinv*h1 (bf16) ----------------
__global__ void k_g3mm1(const int* __restrict__ off, const int* __restrict__ csr,
                        const float* __restrict__ dinv, const float4* __restrict__ xp,
                        const float* __restrict__ W1, const float* __restrict__ b1,
                        unsigned short* __restrict__ T1, int n) {
    __shared__ float w1s[96];
    __shared__ float b1s[32];
    if (threadIdx.x < 96) w1s[threadIdx.x] = W1[threadIdx.x];
    if (threadIdx.x < 32) b1s[threadIdx.x] = b1[threadIdx.x];
    __syncthreads();
    int i = blockIdx.x * TPB + threadIdx.x;
    if (i >= n) return;
    float4 sf = xp[i];  // self (pre-scaled)
    float s0 = sf.x, s1 = sf.y, s2 = sf.z;
    int e = off[i], e1 = off[i + 1];
    for (; e + 3 < e1; e += 4) {
        float4 a = xp[csr[e]];
        float4 c = xp[csr[e + 1]];
        float4 d = xp[csr[e + 2]];
        float4 f = xp[csr[e + 3]];
        s0 += a.x + c.x + d.x + f.x;
        s1 += a.y + c.y + d.y + f.y;
        s2 += a.z + c.z + d.z + f.z;
    }
    for (; e < e1; ++e) {
        float4 a = xp[csr[e]];
        s0 += a.x; s1 += a.y; s2 += a.z;
    }
    float di = dinv[i];
    s0 *= di; s1 *= di; s2 *= di;   // Xa row
    unsigned outw[16];
#pragma unroll
    for (int fp = 0; fp < 16; fp++) {
        float h0 = fmaf(s0, w1s[2 * fp], fmaf(s1, w1s[32 + 2 * fp], fmaf(s2, w1s[64 + 2 * fp], b1s[2 * fp])));
        float h1 = fmaf(s0, w1s[2 * fp + 1], fmaf(s1, w1s[32 + 2 * fp + 1], fmaf(s2, w1s[64 + 2 * fp + 1], b1s[2 * fp + 1])));
        h0 = fmaxf(h0, 0.0f) * di;
        h1 = fmaxf(h1, 0.0f) * di;
        outw[fp] = (unsigned)f2bf(h0) | ((unsigned)f2bf(h1) << 16);
    }
    uint4* o = (uint4*)(T1 + (size_t)i * 32);
    o[0] = make_uint4(outw[0], outw[1], outw[2], outw[3]);
    o[1] = make_uint4(outw[4], outw[5], outw[6], outw[7]);
    o[2] = make_uint4(outw[8], outw[9], outw[10], outw[11]);
    o[3] = make_uint4(outw[12], outw[13], outw[14], outw[15]);
}

#define ACC8(v) do { \
    a0 += bfLO((v).x); a1 += bfHI((v).x); a2 += bfLO((v).y); a3 += bfHI((v).y); \
    a4 += bfLO((v).z); a5 += bfHI((v).z); a6 += bfLO((v).w); a7 += bfHI((v).w); } while (0)

// ---------------- gather F=32 bf16 (pre-scaled, 64B rows = 1 line/edge): 4 lanes/edge, 16 edges/instr ----------------
__global__ void k_gather32b(const int* __restrict__ off, const int* __restrict__ csr,
                            const float* __restrict__ dinv, const unsigned short* __restrict__ T,
                            float* __restrict__ G, int n) {
    int w = (blockIdx.x * TPB + threadIdx.x) >> 6;
    if (w >= n) return;
    int lane = threadIdx.x & 63;
    int grp = lane >> 2, q = lane & 3;   // feats q*8..q*8+7
    float a0 = 0, a1 = 0, a2 = 0, a3 = 0, a4 = 0, a5 = 0, a6 = 0, a7 = 0;
    if (grp == 0) {
        uint4 v = *(const uint4*)(T + ((size_t)w << 5) + (q << 3));
        ACC8(v);  // self (pre-scaled by dinv[w])
    }
    int e = off[w] + grp, e1 = off[w + 1];
    for (; e + 16 < e1; e += 32) {
        int s0 = csr[e], s1 = csr[e + 16];
        uint4 v0 = *(const uint4*)(T + ((size_t)s0 << 5) + (q << 3));
        uint4 v1 = *(const uint4*)(T + ((size_t)s1 << 5) + (q << 3));
        ACC8(v0); ACC8(v1);
    }
    if (e < e1) {
        int s = csr[e];
        uint4 v = *(const uint4*)(T + ((size_t)s << 5) + (q << 3));
        ACC8(v);
    }
#pragma unroll
    for (int m = 4; m < 64; m <<= 1) {
        a0 += __shfl_xor(a0, m); a1 += __shfl_xor(a1, m);
        a2 += __shfl_xor(a2, m); a3 += __shfl_xor(a3, m);
        a4 += __shfl_xor(a4, m); a5 += __shfl_xor(a5, m);
        a6 += __shfl_xor(a6, m); a7 += __shfl_xor(a7, m);
    }
    if (grp == 0) {
        float di = dinv[w];
        float* g = G + ((size_t)w << 5) + (q << 3);
        *(float4*)g = make_float4(a0 * di, a1 * di, a2 * di, a3 * di);
        *(float4*)(g + 4) = make_float4(a4 * di, a5 * di, a6 * di, a7 * di);
    }
}

// ---------------- mm2: one node per lane; T2' = dinv*relu(G1@W2+b2) bf16 + global max ----------------
__global__ void k_mm2(const float* __restrict__ G, const float* __restrict__ W,
                      const float* __restrict__ b, const float* __restrict__ dinv,
                      unsigned short* __restrict__ T, unsigned* __restrict__ gmaxu, int n) {
    int i = blockIdx.x * TPB + threadIdx.x;
    float mx = 0.0f;
    if (i < n) {
        float gr[32];
        const float4* g4 = (const float4*)(G + (size_t)i * 32);
#pragma unroll
        for (int c = 0; c < 8; c++) {
            float4 v = g4[c];
            gr[4 * c] = v.x; gr[4 * c + 1] = v.y; gr[4 * c + 2] = v.z; gr[4 * c + 3] = v.w;
        }
        float di = dinv[i];
        uint2* o = (uint2*)(T + (size_t)i * 64);
        for (int fc = 0; fc < 16; fc++) {  // output chunks of 4
            const float* bb = b + 4 * fc;
            float a0 = bb[0], a1 = bb[1], a2 = bb[2], a3 = bb[3];
#pragma unroll
            for (int k = 0; k < 32; k++) {
                const float* wr = W + k * 64 + 4 * fc;  // wave-uniform address
                float g = gr[k];
                a0 = fmaf(g, wr[0], a0);
                a1 = fmaf(g, wr[1], a1);
                a2 = fmaf(g, wr[2], a2);
                a3 = fmaf(g, wr[3], a3);
            }
            a0 = fmaxf(a0, 0.0f) * di; a1 = fmaxf(a1, 0.0f) * di;
            a2 = fmaxf(a2, 0.0f) * di; a3 = fmaxf(a3, 0.0f) * di;
            mx = fmaxf(mx, fmaxf(fmaxf(a0, a1), fmaxf(a2, a3)));
            o[fc] = make_uint2((unsigned)f2bf(a0) | ((unsigned)f2bf(a1) << 16),
                               (unsigned)f2bf(a2) | ((unsigned)f2bf(a3) << 16));
        }
    }
    // block max -> one global atomic
#pragma unroll
    for (int m = 1; m < 64; m <<= 1) mx = fmaxf(mx, __shfl_xor(mx, m));
    __shared__ float wmax[4];
    if ((threadIdx.x & 63) == 0) wmax[threadIdx.x >> 6] = mx;
    __syncthreads();
    if (threadIdx.x == 0) {
        float m4 = fmaxf(fmaxf(wmax[0], wmax[1]), fmaxf(wmax[2], wmax[3]));
        atomicMax(gmaxu, __float_as_uint(m4));  // values >= 0: uint order == float order
    }
}

// ---------------- quantize T2' bf16 -> T2q u8 with global scale ----------------
__global__ void k_quant(const unsigned short* __restrict__ Tp, const unsigned* __restrict__ gmaxu,
                        unsigned char* __restrict__ Tq, int n8) {
    int j = blockIdx.x * TPB + threadIdx.x;  // 8 elements per thread
    if (j >= n8) return;
    float gm = __uint_as_float(gmaxu[0]);
    float inv = 254.0f / fmaxf(gm, 1e-20f);
    uint4 v = *(const uint4*)(Tp + (size_t)j * 8);
    unsigned q0 = (unsigned)__float2int_rn(bfLO(v.x) * inv);
    unsigned q1 = (unsigned)__float2int_rn(bfHI(v.x) * inv);
    unsigned q2 = (unsigned)__float2int_rn(bfLO(v.y) * inv);
    unsigned q3 = (unsigned)__float2int_rn(bfHI(v.y) * inv);
    unsigned q4 = (unsigned)__float2int_rn(bfLO(v.z) * inv);
    unsigned q5 = (unsigned)__float2int_rn(bfHI(v.z) * inv);
    unsigned q6 = (unsigned)__float2int_rn(bfLO(v.w) * inv);
    unsigned q7 = (unsigned)__float2int_rn(bfHI(v.w) * inv);
    *(uint2*)(Tq + (size_t)j * 8) =
        make_uint2(q0 | (q1 << 8) | (q2 << 16) | (q3 << 24),
                   q4 | (q5 << 8) | (q6 << 16) | (q7 << 24));
}

#define UACC4(word, base) do { \
    a[(base) + 0] += (float)((word) & 0xffu); \
    a[(base) + 1] += (float)(((word) >> 8) & 0xffu); \
    a[(base) + 2] += (float)(((word) >> 16) & 0xffu); \
    a[(base) + 3] += (float)((word) >> 24); } while (0)

#define UACC16(v) do { UACC4((v).x, 0); UACC4((v).y, 4); UACC4((v).z, 8); UACC4((v).w, 12); } while (0)

// ---------------- gather F=64 u8 global-scale: 4 lanes/edge (uint4), 16 edges/instr, 2-deep ----------------
__global__ void k_gather64q(const int* __restrict__ off, const int* __restrict__ csr,
                            const float* __restrict__ dinv, const unsigned char* __restrict__ T,
                            const unsigned* __restrict__ gmaxu, float* __restrict__ G, int n) {
    int w = (blockIdx.x * TPB + threadIdx.x) >> 6;
    if (w >= n) return;
    int lane = threadIdx.x & 63;
    int grp = lane >> 2, q = lane & 3;   // feats q*16 .. q*16+15
    float a[16];
#pragma unroll
    for (int j = 0; j < 16; j++) a[j] = 0.0f;
    if (grp == 0) {
        uint4 v = *(const uint4*)(T + ((size_t)w << 6) + (q << 4));
        UACC16(v);  // self
    }
    int e = off[w] + grp, e1 = off[w + 1];
    for (; e + 16 < e1; e += 32) {
        int s0 = csr[e], s1 = csr[e + 16];
        uint4 v0 = *(const uint4*)(T + ((size_t)s0 << 6) + (q << 4));
        uint4 v1 = *(const uint4*)(T + ((size_t)s1 << 6) + (q << 4));
        UACC16(v0); UACC16(v1);
    }
    if (e < e1) {
        int s = csr[e];
        uint4 v = *(const uint4*)(T + ((size_t)s << 6) + (q << 4));
        UACC16(v);
    }
#pragma unroll
    for (int m = 4; m < 64; m <<= 1) {
#pragma unroll
        for (int j = 0; j < 16; j++) a[j] += __shfl_xor(a[j], m);
    }
    if (grp == 0) {
        float gm = __uint_as_float(gmaxu[0]);
        float s = dinv[w] * (gm * (1.0f / 254.0f));
        float4* g = (float4*)(G + ((size_t)w << 6) + (q << 4));
#pragma unroll
        for (int c = 0; c < 4; c++)
            g[c] = make_float4(a[4 * c] * s, a[4 * c + 1] * s,
                               a[4 * c + 2] * s, a[4 * c + 3] * s);
    }
}

// ---------------- mm3: one node per lane; H = G2@W3 + b3 (fp32, no relu) ----------------
__global__ void k_mm3(const float* __restrict__ G, const float* __restrict__ W,
                      const float* __restrict__ b, float* __restrict__ H, int n) {
    int i = blockIdx.x * TPB + threadIdx.x;
    if (i >= n) return;
    float gr[64];
    const float4* g4 = (const float4*)(G + (size_t)i * 64);
#pragma unroll
    for (int c = 0; c < 16; c++) {
        float4 v = g4[c];
        gr[4 * c] = v.x; gr[4 * c + 1] = v.y; gr[4 * c + 2] = v.z; gr[4 * c + 3] = v.w;
    }
    float4* h4 = (float4*)(H + (size_t)i * 64);
    for (int fc = 0; fc < 16; fc++) {  // output chunks of 4
        const float* bb = b + 4 * fc;
        float a0 = bb[0], a1 = bb[1], a2 = bb[2], a3 = bb[3];
#pragma unroll
        for (int k = 0; k < 64; k++) {
            const float* wr = W + k * 64 + 4 * fc;  // wave-uniform address
            float g = gr[k];
            a0 = fmaf(g, wr[0], a0);
            a1 = fmaf(g, wr[1], a1);
            a2 = fmaf(g, wr[2], a2);
            a3 = fmaf(g, wr[3], a3);
        }
        h4[fc] = make_float4(a0, a1, a2, a3);
    }
}

// ---------------- pool (max & mean per graph) + classifier + softmax ----------------
__global__ void k_pool(const float* __restrict__ H, const float* __restrict__ Wc,
                       const float* __restrict__ bc, float* __restrict__ out,
                       int n, int g_total) {
    int g = blockIdx.x;
    int f = threadIdx.x & 63;
    int c = threadIdx.x >> 6;  // 0..3 chunks
    long long start = ((long long)g * n + g_total - 1) / g_total;
    long long end = ((long long)(g + 1) * n + g_total - 1) / g_total;
    float mx = -INFINITY, sm = 0.0f;
    for (long long i = start + c; i < end; i += 4) {
        float v = H[(i << 6) | f];
        mx = fmaxf(mx, v);
        sm += v;
    }
    __shared__ float smax[4][64], ssum[4][64], slog[2];
    smax[c][f] = mx; ssum[c][f] = sm;
    __syncthreads();
    if (c == 0) {
        mx = fmaxf(fmaxf(smax[0][f], smax[1][f]), fmaxf(smax[2][f], smax[3][f]));
        sm = ssum[0][f] + ssum[1][f] + ssum[2][f] + ssum[3][f];
        long long cnt = end - start;
        smax[0][f] = mx;
        ssum[0][f] = sm / (float)(cnt > 0 ? cnt : 1);
    }
    __syncthreads();
    if (threadIdx.x < 2) {
        int cls = threadIdx.x;
        float l = bc[cls];
        for (int k = 0; k < 64; k++)
            l += smax[0][k] * Wc[k * 2 + cls] + ssum[0][k] * Wc[(64 + k) * 2 + cls];
        slog[cls] = l;
    }
    __syncthreads();
    if (threadIdx.x == 0) {
        float m = fmaxf(slog[0], slog[1]);
        float e0 = expf(slog[0] - m), e1 = expf(slog[1] - m);
        float inv = 1.0f / (e0 + e1);
        out[g * 2 + 0] = e0 * inv;
        out[g * 2 + 1] = e1 * inv;
    }
}

extern "C" void kernel_launch(void* const* d_in, const int* in_sizes, int n_in,
                              void* d_out, int out_size, void* d_ws, size_t ws_size,
                              hipStream_t stream) {
    const float* x  = (const float*)d_in[0];
    const float* W1 = (const float*)d_in[1];
    const float* b1 = (const float*)d_in[2];
    const float* W2 = (const float*)d_in[3];
    const float* b2 = (const float*)d_in[4];
    const float* W3 = (const float*)d_in[5];
    const float* b3 = (const float*)d_in[6];
    const float* Wc = (const float*)d_in[7];
    const float* bc = (const float*)d_in[8];
    const int*   ei = (const int*)d_in[9];

    const int N = in_sizes[0] / 3;
    const int E = in_sizes[9] / 2;
    const int G = out_size / 2;
    const int* src = ei;
    const int* dst = ei + E;

    char* ws = (char*)d_ws;
    size_t off_b = 0;
    auto alloc = [&](size_t bytes) {
        size_t o = off_b;
        off_b = (off_b + bytes + 255) & ~(size_t)255;
        return (void*)(ws + o);
    };
    float*    dinv      = (float*)alloc((size_t)N * 4);
    int*      off       = (int*)alloc((size_t)(N + 1) * 4);
    int*      bucketCnt = (int*)alloc((NB_MAX + 1) * 4);
    int*      bucketOff = (int*)alloc((NB_MAX + 1) * 4);
    int*      bucketCur = (int*)alloc((NB_MAX + 1) * 4);
    int*      csr       = (int*)alloc((size_t)E * 4);
    float4*   xp        = (float4*)alloc((size_t)N * 16);
    unsigned* gmaxu     = (unsigned*)alloc(256);
    size_t bufA_sz = (size_t)N * 64 * 4;                  // G2 fp32 is the max user
    if ((size_t)E * 4 > bufA_sz) bufA_sz = (size_t)E * 4;
    float* bufA = (float*)alloc(bufA_sz);                 // pairs -> G1 -> G2
    float* bufB = (float*)alloc((size_t)N * 64 * 4);      // T1 bf16 / T2' bf16 | T2q u8 -> H fp32

    unsigned* pairs = (unsigned*)bufA;
    float* G1 = bufA;
    float* G2 = bufA;
    unsigned short* T1  = (unsigned short*)bufB;                   // N*64B  [dead after gather32]
    unsigned short* T2p = (unsigned short*)bufB;                   // N*128B (overwrites T1)
    unsigned char*  T2q = (unsigned char*)bufB + (size_t)N * 128;  // N*64B
    float* H = (float*)bufB;                                       // N*256B (all T dead by mm3)

    auto cdiv = [](long long a, long long b) { return (int)((a + b - 1) / b); };
    const int nb = cdiv(N, BKT_NODES);  // coarse buckets (<= NB_MAX)

    // ---- CSR build ----
    hipMemsetAsync(bucketCnt, 0, (size_t)nb * 4, stream);
    hipMemsetAsync(gmaxu, 0, 4, stream);
    k_hist_coarse<<<1024, TPB_H, 0, stream>>>(dst, bucketCnt, E, nb);
    k_scanb<<<1, NB_MAX, 0, stream>>>(bucketCnt, bucketOff, bucketCur, off, nb, E, N);
    k_bin_pairs<<<cdiv(E, BIN_CHUNK), TPB_BIN, 0, stream>>>(src, dst, bucketCur, pairs, E, nb);
    k_bucket_csr<<<nb, CSR_TPB, 0, stream>>>(pairs, bucketOff, off, dinv, csr, N);

    // ---- layer 1 (fused): xp4 = dinv*x (16B rows); T1' = dinv*relu(S'x'@W1+b1) bf16 ----
    k_scale4<<<cdiv(N, TPB), TPB, 0, stream>>>(x, dinv, xp, N);
    k_g3mm1<<<cdiv(N, TPB), TPB, 0, stream>>>(off, csr, dinv, xp, W1, b1, T1, N);

    // ---- layer 2: G1 = dinv*(sum T1') bf16 gather (1 line/edge); T2' bf16 + global max ----
    k_gather32b<<<cdiv((long long)N * 64, TPB), TPB, 0, stream>>>(off, csr, dinv, T1, G1, N);
    k_mm2<<<cdiv(N, TPB), TPB, 0, stream>>>(G1, W2, b2, dinv, T2p, gmaxu, N);

    // ---- quantize to u8 with global scale; layer 3 gather = 1 line/edge, 16 edges/instr ----
    k_quant<<<cdiv((long long)N * 8, TPB), TPB, 0, stream>>>(T2p, gmaxu, T2q, N * 8);
    k_gather64q<<<cdiv((long long)N * 64, TPB), TPB, 0, stream>>>(off, csr, dinv, T2q, gmaxu, G2, N);
    k_mm3<<<cdiv(N, TPB), TPB, 0, stream>>>(G2, W3, b3, H, N);

    // ---- pool + classify + softmax ----
    k_pool<<<G, TPB, 0, stream>>>(H, Wc, bc, (float*)d_out, N, G);
}

// Round 14
// 294.915 us; speedup vs baseline: 1.0533x; 1.0533x over previous
//
#include <hip/hip_runtime.h>
#include <math.h>

#define TPB 256
#define TPB_H 512
#define TPB_BIN 1024
#define CSR_TPB 1024
#define NB_MAX 512      // coarse buckets of 256 nodes -> supports N <= 131072
#define BKT_SHIFT 8
#define BKT_NODES 256
#define BIN_CHUNK 8192

__device__ inline float bfLO(unsigned u) { return __uint_as_float(u << 16); }
__device__ inline float bfHI(unsigned u) { return __uint_as_float(u & 0xffff0000u); }
__device__ inline unsigned short f2bf(float f) {
    unsigned int x = __float_as_uint(f);
    return (unsigned short)((x + 0x7fffu + ((x >> 16) & 1u)) >> 16);  // RNE
}

// ---------------- pass A: coarse bucket histogram (LDS, int4 loads) ----------------
__global__ void k_hist_coarse(const int* __restrict__ dst, int* __restrict__ bucketCnt,
                              int e, int nb) {
    __shared__ int h[NB_MAX];
    for (int i = threadIdx.x; i < nb; i += TPB_H) h[i] = 0;
    __syncthreads();
    int e4 = e >> 2;
    const int4* d4 = (const int4*)dst;
    for (long long i = (long long)blockIdx.x * TPB_H + threadIdx.x; i < e4;
         i += (long long)gridDim.x * TPB_H) {
        int4 v = d4[i];
        atomicAdd(&h[v.x >> BKT_SHIFT], 1);
        atomicAdd(&h[v.y >> BKT_SHIFT], 1);
        atomicAdd(&h[v.z >> BKT_SHIFT], 1);
        atomicAdd(&h[v.w >> BKT_SHIFT], 1);
    }
    if (blockIdx.x == 0)
        for (int i = (e4 << 2) + threadIdx.x; i < e; i += TPB_H)
            atomicAdd(&h[dst[i] >> BKT_SHIFT], 1);
    __syncthreads();
    for (int i = threadIdx.x; i < nb; i += TPB_H)
        if (h[i]) atomicAdd(&bucketCnt[i], h[i]);
}

// ---------------- parallel bucket scan (1 block) ----------------
__global__ void k_scanb(const int* __restrict__ cnt, int* __restrict__ boff,
                        int* __restrict__ bcur, int* __restrict__ off_nodes,
                        int nb, int e, int n) {
    __shared__ int lds[NB_MAX];
    int t = threadIdx.x;
    int v = (t < nb) ? cnt[t] : 0;
    lds[t] = v;
    __syncthreads();
    for (int d = 1; d < NB_MAX; d <<= 1) {
        int x = (t >= d) ? lds[t - d] : 0;
        __syncthreads();
        lds[t] += x;
        __syncthreads();
    }
    int excl = lds[t] - v;
    if (t < nb) { boff[t] = excl; bcur[t] = excl; }
    if (t == nb - 1) boff[nb] = lds[t];
    if (t == 0) off_nodes[n] = e;
}

// ---------------- pass B: bin packed (src | local_dst<<24) by coarse bucket ----------------
__global__ void k_bin_pairs(const int* __restrict__ src, const int* __restrict__ dst,
                            int* __restrict__ bucketCur, unsigned* __restrict__ pairs,
                            int e, int nb) {
    __shared__ int h[NB_MAX];
    __shared__ int base[NB_MAX];
    int e0 = blockIdx.x * BIN_CHUNK;
    int e1 = min(e0 + BIN_CHUNK, e);
    for (int i = threadIdx.x; i < nb; i += TPB_BIN) h[i] = 0;
    __syncthreads();
    for (int i = e0 + threadIdx.x; i < e1; i += TPB_BIN)
        atomicAdd(&h[dst[i] >> BKT_SHIFT], 1);
    __syncthreads();
    for (int i = threadIdx.x; i < nb; i += TPB_BIN) {
        int c = h[i];
        base[i] = c ? atomicAdd(&bucketCur[i], c) : 0;
        h[i] = 0;  // reuse as intra-block cursor
    }
    __syncthreads();
    for (int i = e0 + threadIdx.x; i < e1; i += TPB_BIN) {
        int d = dst[i];
        int b = d >> BKT_SHIFT;
        int pos = base[b] + atomicAdd(&h[b], 1);
        pairs[pos] = ((unsigned)(d & (BKT_NODES - 1)) << 24) | (unsigned)src[i];
    }
}

// ---------------- pass C: per-bucket fine CSR + node offsets + dinv ----------------
__global__ void k_bucket_csr(const unsigned* __restrict__ pairs, const int* __restrict__ bucketOff,
                             int* __restrict__ off_nodes, float* __restrict__ dinv,
                             int* __restrict__ csr, int n) {
    __shared__ int hist[BKT_NODES];
    __shared__ int offl[BKT_NODES];
    __shared__ int cur[BKT_NODES];
    int b = blockIdx.x;
    int t = threadIdx.x;  // CSR_TPB threads
    int e0 = bucketOff[b], e1 = bucketOff[b + 1];
    int nbase = b << BKT_SHIFT;
    if (t < BKT_NODES) hist[t] = 0;
    __syncthreads();
    for (int e = e0 + t; e < e1; e += CSR_TPB)
        atomicAdd(&hist[pairs[e] >> 24], 1);
    __syncthreads();
    int v = 0;
    if (t < BKT_NODES) { v = hist[t]; offl[t] = v; }
    __syncthreads();
    for (int d = 1; d < BKT_NODES; d <<= 1) {
        int x = 0;
        if (t < BKT_NODES && t >= d) x = offl[t - d];
        __syncthreads();
        if (t < BKT_NODES) offl[t] += x;
        __syncthreads();
    }
    if (t < BKT_NODES) {
        int excl = offl[t] - v;
        cur[t] = excl;
        int nd = nbase + t;
        if (nd < n) {
            off_nodes[nd] = e0 + excl;
            dinv[nd] = rsqrtf((float)(v + 1));  // +1 self loop
        }
    }
    __syncthreads();
    for (int e = e0 + t; e < e1; e += CSR_TPB) {
        unsigned p = pairs[e];
        int l = (int)(p >> 24);
        int pos = e0 + atomicAdd(&cur[l], 1);
        csr[pos] = (int)(p & 0xffffffu);
    }
}

// ---------------- xp4 = float4(dinv*x, pad) ----------------
__global__ void k_scale4(const float* __restrict__ x, const float* __restrict__ dinv,
                         float4* __restrict__ xp, int n) {
    int i = blockIdx.x * TPB + threadIdx.x;
    if (i >= n) return;
    float di = dinv[i];
    xp[i] = make_float4(x[i * 3] * di, x[i * 3 + 1] * di, x[i * 3 + 2] * di, 0.0f);
}

// ---------------- fused gather(F=3, float4 rows) + mm1 + relu -> T1' = dinv*h1 (bf16) ----------------
__global__ void k_g3mm1(const int* __restrict__ off, const int* __restrict__ csr,
                        const float* __restrict__ dinv, const float4* __restrict__ xp,
                        const float* __restrict__ W1, const float* __restrict__ b1,
                        unsigned short* __restrict__ T1, int n) {
    __shared__ float w1s[96];
    __shared__ float b1s[32];
    if (threadIdx.x < 96) w1s[threadIdx.x] = W1[threadIdx.x];
    if (threadIdx.x < 32) b1s[threadIdx.x] = b1[threadIdx.x];
    __syncthreads();
    int i = blockIdx.x * TPB + threadIdx.x;
    if (i >= n) return;
    float4 sf = xp[i];  // self (pre-scaled)
    float s0 = sf.x, s1 = sf.y, s2 = sf.z;
    int e = off[i], e1 = off[i + 1];
    for (; e + 3 < e1; e += 4) {
        float4 a = xp[csr[e]];
        float4 c = xp[csr[e + 1]];
        float4 d = xp[csr[e + 2]];
        float4 f = xp[csr[e + 3]];
        s0 += a.x + c.x + d.x + f.x;
        s1 += a.y + c.y + d.y + f.y;
        s2 += a.z + c.z + d.z + f.z;
    }
    for (; e < e1; ++e) {
        float4 a = xp[csr[e]];
        s0 += a.x; s1 += a.y; s2 += a.z;
    }
    float di = dinv[i];
    s0 *= di; s1 *= di; s2 *= di;   // Xa row
    unsigned outw[16];
#pragma unroll
    for (int fp = 0; fp < 16; fp++) {
        float h0 = fmaf(s0, w1s[2 * fp], fmaf(s1, w1s[32 + 2 * fp], fmaf(s2, w1s[64 + 2 * fp], b1s[2 * fp])));
        float h1 = fmaf(s0, w1s[2 * fp + 1], fmaf(s1, w1s[32 + 2 * fp + 1], fmaf(s2, w1s[64 + 2 * fp + 1], b1s[2 * fp + 1])));
        h0 = fmaxf(h0, 0.0f) * di;
        h1 = fmaxf(h1, 0.0f) * di;
        outw[fp] = (unsigned)f2bf(h0) | ((unsigned)f2bf(h1) << 16);
    }
    uint4* o = (uint4*)(T1 + (size_t)i * 32);
    o[0] = make_uint4(outw[0], outw[1], outw[2], outw[3]);
    o[1] = make_uint4(outw[4], outw[5], outw[6], outw[7]);
    o[2] = make_uint4(outw[8], outw[9], outw[10], outw[11]);
    o[3] = make_uint4(outw[12], outw[13], outw[14], outw[15]);
}

#define ACC8(v) do { \
    a0 += bfLO((v).x); a1 += bfHI((v).x); a2 += bfLO((v).y); a3 += bfHI((v).y); \
    a4 += bfLO((v).z); a5 += bfHI((v).z); a6 += bfLO((v).w); a7 += bfHI((v).w); } while (0)

// ---------------- gather F=32 bf16 (pre-scaled, 64B rows = 1 line/edge): 4 lanes/edge ----------------
__global__ void k_gather32b(const int* __restrict__ off, const int* __restrict__ csr,
                            const float* __restrict__ dinv, const unsigned short* __restrict__ T,
                            float* __restrict__ G, int n) {
    int w = (blockIdx.x * TPB + threadIdx.x) >> 6;
    if (w >= n) return;
    int lane = threadIdx.x & 63;
    int grp = lane >> 2, q = lane & 3;   // feats q*8..q*8+7
    float a0 = 0, a1 = 0, a2 = 0, a3 = 0, a4 = 0, a5 = 0, a6 = 0, a7 = 0;
    if (grp == 0) {
        uint4 v = *(const uint4*)(T + ((size_t)w << 5) + (q << 3));
        ACC8(v);  // self (pre-scaled by dinv[w])
    }
    int e = off[w] + grp, e1 = off[w + 1];
    for (; e + 16 < e1; e += 32) {
        int s0 = csr[e], s1 = csr[e + 16];
        uint4 v0 = *(const uint4*)(T + ((size_t)s0 << 5) + (q << 3));
        uint4 v1 = *(const uint4*)(T + ((size_t)s1 << 5) + (q << 3));
        ACC8(v0); ACC8(v1);
    }
    if (e < e1) {
        int s = csr[e];
        uint4 v = *(const uint4*)(T + ((size_t)s << 5) + (q << 3));
        ACC8(v);
    }
#pragma unroll
    for (int m = 4; m < 64; m <<= 1) {
        a0 += __shfl_xor(a0, m); a1 += __shfl_xor(a1, m);
        a2 += __shfl_xor(a2, m); a3 += __shfl_xor(a3, m);
        a4 += __shfl_xor(a4, m); a5 += __shfl_xor(a5, m);
        a6 += __shfl_xor(a6, m); a7 += __shfl_xor(a7, m);
    }
    if (grp == 0) {
        float di = dinv[w];
        float* g = G + ((size_t)w << 5) + (q << 3);
        *(float4*)g = make_float4(a0 * di, a1 * di, a2 * di, a3 * di);
        *(float4*)(g + 4) = make_float4(a4 * di, a5 * di, a6 * di, a7 * di);
    }
}

// ---------------- mm2: one node per lane; T2' = dinv*relu(G1@W2+b2) bf16 + global max ----------------
__global__ void k_mm2(const float* __restrict__ G, const float* __restrict__ W,
                      const float* __restrict__ b, const float* __restrict__ dinv,
                      unsigned short* __restrict__ T, unsigned* __restrict__ gmaxu, int n) {
    int i = blockIdx.x * TPB + threadIdx.x;
    float mx = 0.0f;
    if (i < n) {
        float gr[32];
        const float4* g4 = (const float4*)(G + (size_t)i * 32);
#pragma unroll
        for (int c = 0; c < 8; c++) {
            float4 v = g4[c];
            gr[4 * c] = v.x; gr[4 * c + 1] = v.y; gr[4 * c + 2] = v.z; gr[4 * c + 3] = v.w;
        }
        float di = dinv[i];
        uint2* o = (uint2*)(T + (size_t)i * 64);
        for (int fc = 0; fc < 16; fc++) {  // output chunks of 4
            const float* bb = b + 4 * fc;
            float a0 = bb[0], a1 = bb[1], a2 = bb[2], a3 = bb[3];
#pragma unroll
            for (int k = 0; k < 32; k++) {
                const float* wr = W + k * 64 + 4 * fc;  // wave-uniform address
                float g = gr[k];
                a0 = fmaf(g, wr[0], a0);
                a1 = fmaf(g, wr[1], a1);
                a2 = fmaf(g, wr[2], a2);
                a3 = fmaf(g, wr[3], a3);
            }
            a0 = fmaxf(a0, 0.0f) * di; a1 = fmaxf(a1, 0.0f) * di;
            a2 = fmaxf(a2, 0.0f) * di; a3 = fmaxf(a3, 0.0f) * di;
            mx = fmaxf(mx, fmaxf(fmaxf(a0, a1), fmaxf(a2, a3)));
            o[fc] = make_uint2((unsigned)f2bf(a0) | ((unsigned)f2bf(a1) << 16),
                               (unsigned)f2bf(a2) | ((unsigned)f2bf(a3) << 16));
        }
    }
    // block max -> one global atomic
#pragma unroll
    for (int m = 1; m < 64; m <<= 1) mx = fmaxf(mx, __shfl_xor(mx, m));
    __shared__ float wmax[4];
    if ((threadIdx.x & 63) == 0) wmax[threadIdx.x >> 6] = mx;
    __syncthreads();
    if (threadIdx.x == 0) {
        float m4 = fmaxf(fmaxf(wmax[0], wmax[1]), fmaxf(wmax[2], wmax[3]));
        atomicMax(gmaxu, __float_as_uint(m4));  // values >= 0: uint order == float order
    }
}

// ---------------- quantize T2' bf16 -> T2q u8 with global scale ----------------
__global__ void k_quant(const unsigned short* __restrict__ Tp, const unsigned* __restrict__ gmaxu,
                        unsigned char* __restrict__ Tq, int n8) {
    int j = blockIdx.x * TPB + threadIdx.x;  // 8 elements per thread
    if (j >= n8) return;
    float gm = __uint_as_float(gmaxu[0]);
    float inv = 254.0f / fmaxf(gm, 1e-20f);
    uint4 v = *(const uint4*)(Tp + (size_t)j * 8);
    unsigned q0 = (unsigned)__float2int_rn(bfLO(v.x) * inv);
    unsigned q1 = (unsigned)__float2int_rn(bfHI(v.x) * inv);
    unsigned q2 = (unsigned)__float2int_rn(bfLO(v.y) * inv);
    unsigned q3 = (unsigned)__float2int_rn(bfHI(v.y) * inv);
    unsigned q4 = (unsigned)__float2int_rn(bfLO(v.z) * inv);
    unsigned q5 = (unsigned)__float2int_rn(bfHI(v.z) * inv);
    unsigned q6 = (unsigned)__float2int_rn(bfLO(v.w) * inv);
    unsigned q7 = (unsigned)__float2int_rn(bfHI(v.w) * inv);
    *(uint2*)(Tq + (size_t)j * 8) =
        make_uint2(q0 | (q1 << 8) | (q2 << 16) | (q3 << 24),
                   q4 | (q5 << 8) | (q6 << 16) | (q7 << 24));
}

#define UACC8(v) do { \
    a0 += (float)((v).x & 0xffu); a1 += (float)(((v).x >> 8) & 0xffu); \
    a2 += (float)(((v).x >> 16) & 0xffu); a3 += (float)((v).x >> 24); \
    a4 += (float)((v).y & 0xffu); a5 += (float)(((v).y >> 8) & 0xffu); \
    a6 += (float)(((v).y >> 16) & 0xffu); a7 += (float)((v).y >> 24); } while (0)

// ---------------- gather F=64 u8 global-scale (64B rows = 1 line/edge): 8 lanes/edge, 2-deep ----------------
__global__ void k_gather64q(const int* __restrict__ off, const int* __restrict__ csr,
                            const float* __restrict__ dinv, const unsigned char* __restrict__ T,
                            const unsigned* __restrict__ gmaxu, float* __restrict__ G, int n) {
    int w = (blockIdx.x * TPB + threadIdx.x) >> 6;
    if (w >= n) return;
    int lane = threadIdx.x & 63;
    int grp = lane >> 3, q = lane & 7;   // feats q*8..q*8+7
    float a0 = 0, a1 = 0, a2 = 0, a3 = 0, a4 = 0, a5 = 0, a6 = 0, a7 = 0;
    if (grp == 0) {
        uint2 v = *(const uint2*)(T + ((size_t)w << 6) + (q << 3));
        UACC8(v);  // self
    }
    int e = off[w] + grp, e1 = off[w + 1];
    for (; e + 8 < e1; e += 16) {
        int s0 = csr[e], s1 = csr[e + 8];
        uint2 v0 = *(const uint2*)(T + ((size_t)s0 << 6) + (q << 3));
        uint2 v1 = *(const uint2*)(T + ((size_t)s1 << 6) + (q << 3));
        UACC8(v0); UACC8(v1);
    }
    if (e < e1) {
        int s = csr[e];
        uint2 v = *(const uint2*)(T + ((size_t)s << 6) + (q << 3));
        UACC8(v);
    }
#pragma unroll
    for (int m = 8; m < 64; m <<= 1) {
        a0 += __shfl_xor(a0, m); a1 += __shfl_xor(a1, m);
        a2 += __shfl_xor(a2, m); a3 += __shfl_xor(a3, m);
        a4 += __shfl_xor(a4, m); a5 += __shfl_xor(a5, m);
        a6 += __shfl_xor(a6, m); a7 += __shfl_xor(a7, m);
    }
    if (grp == 0) {
        float gm = __uint_as_float(gmaxu[0]);
        float s = dinv[w] * (gm * (1.0f / 254.0f));
        float* g = G + ((size_t)w << 6) + (q << 3);
        *(float4*)g = make_float4(a0 * s, a1 * s, a2 * s, a3 * s);
        *(float4*)(g + 4) = make_float4(a4 * s, a5 * s, a6 * s, a7 * s);
    }
}

// ---------------- mm3: one node per lane; H = G2@W3 + b3 (fp32, no relu) ----------------
__global__ void k_mm3(const float* __restrict__ G, const float* __restrict__ W,
                      const float* __restrict__ b, float* __restrict__ H, int n) {
    int i = blockIdx.x * TPB + threadIdx.x;
    if (i >= n) return;
    float gr[64];
    const float4* g4 = (const float4*)(G + (size_t)i * 64);
#pragma unroll
    for (int c = 0; c < 16; c++) {
        float4 v = g4[c];
        gr[4 * c] = v.x; gr[4 * c + 1] = v.y; gr[4 * c + 2] = v.z; gr[4 * c + 3] = v.w;
    }
    float4* h4 = (float4*)(H + (size_t)i * 64);
    for (int fc = 0; fc < 16; fc++) {  // output chunks of 4
        const float* bb = b + 4 * fc;
        float a0 = bb[0], a1 = bb[1], a2 = bb[2], a3 = bb[3];
#pragma unroll
        for (int k = 0; k < 64; k++) {
            const float* wr = W + k * 64 + 4 * fc;  // wave-uniform address
            float g = gr[k];
            a0 = fmaf(g, wr[0], a0);
            a1 = fmaf(g, wr[1], a1);
            a2 = fmaf(g, wr[2], a2);
            a3 = fmaf(g, wr[3], a3);
        }
        h4[fc] = make_float4(a0, a1, a2, a3);
    }
}

// ---------------- pool (max & mean per graph) + classifier + softmax ----------------
__global__ void k_pool(const float* __restrict__ H, const float* __restrict__ Wc,
                       const float* __restrict__ bc, float* __restrict__ out,
                       int n, int g_total) {
    int g = blockIdx.x;
    int f = threadIdx.x & 63;
    int c = threadIdx.x >> 6;  // 0..3 chunks
    long long start = ((long long)g * n + g_total - 1) / g_total;
    long long end = ((long long)(g + 1) * n + g_total - 1) / g_total;
    float mx = -INFINITY, sm = 0.0f;
    for (long long i = start + c; i < end; i += 4) {
        float v = H[(i << 6) | f];
        mx = fmaxf(mx, v);
        sm += v;
    }
    __shared__ float smax[4][64], ssum[4][64], slog[2];
    smax[c][f] = mx; ssum[c][f] = sm;
    __syncthreads();
    if (c == 0) {
        mx = fmaxf(fmaxf(smax[0][f], smax[1][f]), fmaxf(smax[2][f], smax[3][f]));
        sm = ssum[0][f] + ssum[1][f] + ssum[2][f] + ssum[3][f];
        long long cnt = end - start;
        smax[0][f] = mx;
        ssum[0][f] = sm / (float)(cnt > 0 ? cnt : 1);
    }
    __syncthreads();
    if (threadIdx.x < 2) {
        int cls = threadIdx.x;
        float l = bc[cls];
        for (int k = 0; k < 64; k++)
            l += smax[0][k] * Wc[k * 2 + cls] + ssum[0][k] * Wc[(64 + k) * 2 + cls];
        slog[cls] = l;
    }
    __syncthreads();
    if (threadIdx.x == 0) {
        float m = fmaxf(slog[0], slog[1]);
        float e0 = expf(slog[0] - m), e1 = expf(slog[1] - m);
        float inv = 1.0f / (e0 + e1);
        out[g * 2 + 0] = e0 * inv;
        out[g * 2 + 1] = e1 * inv;
    }
}

extern "C" void kernel_launch(void* const* d_in, const int* in_sizes, int n_in,
                              void* d_out, int out_size, void* d_ws, size_t ws_size,
                              hipStream_t stream) {
    const float* x  = (const float*)d_in[0];
    const float* W1 = (const float*)d_in[1];
    const float* b1 = (const float*)d_in[2];
    const float* W2 = (const float*)d_in[3];
    const float* b2 = (const float*)d_in[4];
    const float* W3 = (const float*)d_in[5];
    const float* b3 = (const float*)d_in[6];
    const float* Wc = (const float*)d_in[7];
    const float* bc = (const float*)d_in[8];
    const int*   ei = (const int*)d_in[9];

    const int N = in_sizes[0] / 3;
    const int E = in_sizes[9] / 2;
    const int G = out_size / 2;
    const int* src = ei;
    const int* dst = ei + E;

    char* ws = (char*)d_ws;
    size_t off_b = 0;
    auto alloc = [&](size_t bytes) {
        size_t o = off_b;
        off_b = (off_b + bytes + 255) & ~(size_t)255;
        return (void*)(ws + o);
    };
    float*    dinv      = (float*)alloc((size_t)N * 4);
    int*      off       = (int*)alloc((size_t)(N + 1) * 4);
    int*      bucketCnt = (int*)alloc((NB_MAX + 1) * 4);
    int*      bucketOff = (int*)alloc((NB_MAX + 1) * 4);
    int*      bucketCur = (int*)alloc((NB_MAX + 1) * 4);
    int*      csr       = (int*)alloc((size_t)E * 4);
    float4*   xp        = (float4*)alloc((size_t)N * 16);
    unsigned* gmaxu     = (unsigned*)alloc(256);
    size_t bufA_sz = (size_t)N * 64 * 4;                  // G2 fp32 is the max user
    if ((size_t)E * 4 > bufA_sz) bufA_sz = (size_t)E * 4;
    float* bufA = (float*)alloc(bufA_sz);                 // pairs -> G1 -> G2
    float* bufB = (float*)alloc((size_t)N * 64 * 4);      // T1 bf16 / T2' bf16 | T2q u8 -> H fp32

    unsigned* pairs = (unsigned*)bufA;
    float* G1 = bufA;
    float* G2 = bufA;
    unsigned short* T1  = (unsigned short*)bufB;                   // N*64B  [dead after gather32]
    unsigned short* T2p = (unsigned short*)bufB;                   // N*128B (overwrites T1)
    unsigned char*  T2q = (unsigned char*)bufB + (size_t)N * 128;  // N*64B
    float* H = (float*)bufB;                                       // N*256B (all T dead by mm3)

    auto cdiv = [](long long a, long long b) { return (int)((a + b - 1) / b); };
    const int nb = cdiv(N, BKT_NODES);  // coarse buckets (<= NB_MAX)

    // ---- CSR build ----
    hipMemsetAsync(bucketCnt, 0, (size_t)nb * 4, stream);
    hipMemsetAsync(gmaxu, 0, 4, stream);
    k_hist_coarse<<<1024, TPB_H, 0, stream>>>(dst, bucketCnt, E, nb);
    k_scanb<<<1, NB_MAX, 0, stream>>>(bucketCnt, bucketOff, bucketCur, off, nb, E, N);
    k_bin_pairs<<<cdiv(E, BIN_CHUNK), TPB_BIN, 0, stream>>>(src, dst, bucketCur, pairs, E, nb);
    k_bucket_csr<<<nb, CSR_TPB, 0, stream>>>(pairs, bucketOff, off, dinv, csr, N);

    // ---- layer 1 (fused): xp4 = dinv*x (16B rows); T1' = dinv*relu(S'x'@W1+b1) bf16 ----
    k_scale4<<<cdiv(N, TPB), TPB, 0, stream>>>(x, dinv, xp, N);
    k_g3mm1<<<cdiv(N, TPB), TPB, 0, stream>>>(off, csr, dinv, xp, W1, b1, T1, N);

    // ---- layer 2: G1 = dinv*(sum T1') bf16 gather (1 line/edge); T2' bf16 + global max ----
    k_gather32b<<<cdiv((long long)N * 64, TPB), TPB, 0, stream>>>(off, csr, dinv, T1, G1, N);
    k_mm2<<<cdiv(N, TPB), TPB, 0, stream>>>(G1, W2, b2, dinv, T2p, gmaxu, N);

    // ---- quantize to u8 with global scale; layer 3 gather = 1 line/edge ----
    k_quant<<<cdiv((long long)N * 8, TPB), TPB, 0, stream>>>(T2p, gmaxu, T2q, N * 8);
    k_gather64q<<<cdiv((long long)N * 64, TPB), TPB, 0, stream>>>(off, csr, dinv, T2q, gmaxu, G2, N);
    k_mm3<<<cdiv(N, TPB), TPB, 0, stream>>>(G2, W3, b3, H, N);

    // ---- pool + classify + softmax ----
    k_pool<<<G, TPB, 0, stream>>>(H, Wc, bc, (float*)d_out, N, G);
}